// Round 1
// baseline (229.420 us; speedup 1.0000x reference)
//
#include <hip/hip_runtime.h>

typedef unsigned short u16;
typedef __bf16 bf16x8 __attribute__((ext_vector_type(8)));
typedef float f32x4 __attribute__((ext_vector_type(4)));

#define LOG2E 1.44269504088896340736f

__device__ __forceinline__ u16 f2bf(float f) {
  unsigned int u = __builtin_bit_cast(unsigned int, f);
  u += 0x7FFFu + ((u >> 16) & 1u);
  return (u16)(u >> 16);
}

__device__ __forceinline__ void async16(const void* g, void* l) {
  __builtin_amdgcn_global_load_lds((void*)g, (void*)l, 16, 0, 0);
}

// ---------------- cast fp32 -> bf16, 4 elems/thread ----------------
__global__ void cast_f32_bf16(const float* __restrict__ src, u16* __restrict__ dst, int n4) {
  int i = blockIdx.x * blockDim.x + threadIdx.x;
  if (i >= n4) return;
  float4 v = ((const float4*)src)[i];
  union { u16 s[4]; uint2 u; } o;
  o.s[0] = f2bf(v.x); o.s[1] = f2bf(v.y); o.s[2] = f2bf(v.z); o.s[3] = f2bf(v.w);
  ((uint2*)dst)[i] = o.u;
}

// ---------------- bf16 NT GEMM: C[m][n] = sum_k A[m][k] * Bw[n][k] ----------------
// 128x128 tile, BK=32, 4 waves each 64x64. EPI 0: QKV scatter. EPI 1: fp32 out + bias.
template <int EPI>
__global__ __launch_bounds__(256)
void gemm_nt(const u16* __restrict__ A, const u16* __restrict__ Bw,
             int M, int N, int K, const float* __restrict__ bias,
             u16* __restrict__ qo, u16* __restrict__ ko, u16* __restrict__ vto,
             float* __restrict__ out, int ntn) {
  __shared__ __align__(16) u16 As[128 * 32];
  __shared__ __align__(16) u16 Bs[128 * 32];
  const int tid = threadIdx.x;
  const int w = tid >> 6, lane = tid & 63;
  const int lr = lane & 15, lkb = lane >> 4;
  const int bx = blockIdx.x;
  const int mt = bx / ntn, nt = bx % ntn;
  const int m0 = mt * 128, n0 = nt * 128;
  const int wm = (w >> 1) * 64, wn = (w & 1) * 64;

  f32x4 acc[4][4] = {};

  int srow[2], sgch[2];
#pragma unroll
  for (int i = 0; i < 2; ++i) {
    int cid = tid + i * 256;          // chunk id: 512 chunks of 16B per 8KB tile
    srow[i] = cid >> 2;               // 4 chunks per 64B row
    sgch[i] = (cid & 3) ^ (srow[i] & 3);  // pre-swizzled source chunk
  }

  for (int k0 = 0; k0 < K; k0 += 32) {
#pragma unroll
    for (int i = 0; i < 2; ++i) {
      char* la = (char*)As + (w * 64 + i * 256) * 16;  // wave-uniform base
      async16(A + (size_t)(m0 + srow[i]) * K + k0 + sgch[i] * 8, la);
      char* lb = (char*)Bs + (w * 64 + i * 256) * 16;
      async16(Bw + (size_t)(n0 + srow[i]) * K + k0 + sgch[i] * 8, lb);
    }
    __syncthreads();

    bf16x8 af[4], bfr[4];
#pragma unroll
    for (int i = 0; i < 4; ++i) {
      int ra = wm + i * 16 + lr;
      af[i] = *(const bf16x8*)(As + ra * 32 + (lkb ^ (ra & 3)) * 8);
      int rb = wn + i * 16 + lr;
      bfr[i] = *(const bf16x8*)(Bs + rb * 32 + (lkb ^ (rb & 3)) * 8);
    }
#pragma unroll
    for (int i = 0; i < 4; ++i)
#pragma unroll
      for (int j = 0; j < 4; ++j)
        acc[i][j] = __builtin_amdgcn_mfma_f32_16x16x32_bf16(af[i], bfr[j], acc[i][j], 0, 0, 0);
    __syncthreads();
  }

  if constexpr (EPI == 0) {
    // QKV scatter epilogue. n = which*1024 + h*64 + dd ; m = b*2048 + s
    const int which = n0 >> 10;  // uniform per block (128 | 1024)
    const float qscale = (which == 0) ? 0.125f : 1.0f;  // fold hd^-0.5 into Q
#pragma unroll
    for (int i = 0; i < 4; ++i) {
#pragma unroll
      for (int j = 0; j < 4; ++j) {
        int n = n0 + wn + j * 16 + lr;
        float bv = bias[n];
        int d = n & 1023, h = d >> 6, dd = d & 63;
#pragma unroll
        for (int r = 0; r < 4; ++r) {
          int m = m0 + wm + i * 16 + lkb * 4 + r;
          int b = m >> 11, s = m & 2047;
          int bh = b * 16 + h;
          u16 val = f2bf((acc[i][j][r] + bv) * qscale);
          if (which == 0)      qo[(bh * 2048 + s) * 64 + dd] = val;
          else if (which == 1) ko[(bh * 2048 + s) * 64 + dd] = val;
          else                 vto[(bh * 64 + dd) * 2048 + s] = val;
        }
      }
    }
  } else {
#pragma unroll
    for (int i = 0; i < 4; ++i)
#pragma unroll
      for (int j = 0; j < 4; ++j) {
        int n = n0 + wn + j * 16 + lr;
        float bv = bias[n];
#pragma unroll
        for (int r = 0; r < 4; ++r) {
          int m = m0 + wm + i * 16 + lkb * 4 + r;
          out[(size_t)m * N + n] = acc[i][j][r] + bv;
        }
      }
  }
}

// ---------------- causal flash attention ----------------
// Q,K: [BH=32][S=2048][64] bf16 (Q pre-scaled). Vt: [BH][64][S]. ctx: [B,S,1024] bf16.
// Block: 64 q-rows (4 waves x 16 rows). KV tile = 64. Grid 1024, heavy tiles first.
__global__ __launch_bounds__(256)
void flash_attn(const u16* __restrict__ Q, const u16* __restrict__ Kg,
                const u16* __restrict__ Vt, u16* __restrict__ ctx) {
  __shared__ __align__(16) u16 Kls[64 * 64];
  __shared__ __align__(16) u16 Vls[64 * 64];
  __shared__ __align__(16) u16 Pls[4][16 * 72];
  const int tid = threadIdx.x;
  const int w = tid >> 6, lane = tid & 63;
  const int lr = lane & 15, lkb = lane >> 4;
  const int bid = blockIdx.x;
  const int qt = 31 - (bid >> 5);  // heavy q-tiles scheduled first
  const int bh = bid & 31;
  const int q0 = qt * 64;
  const u16* Qh = Q + (size_t)bh * 2048 * 64;
  const u16* Kh = Kg + (size_t)bh * 2048 * 64;
  const u16* Vh = Vt + (size_t)bh * 2048 * 64;  // [64][2048]

  bf16x8 aQ[2];
#pragma unroll
  for (int kk = 0; kk < 2; ++kk)
    aQ[kk] = *(const bf16x8*)(Qh + (q0 + w * 16 + lr) * 64 + lkb * 8 + kk * 32);

  f32x4 acc[4] = {};
  float mrow[4] = {-1e30f, -1e30f, -1e30f, -1e30f};
  float lrow[4] = {0.f, 0.f, 0.f, 0.f};

  int srow[2], sgch[2];
#pragma unroll
  for (int i = 0; i < 2; ++i) {
    int cid = tid + i * 256;          // 512 chunks per 8KB tile, 8 chunks/128B row
    srow[i] = cid >> 3;
    sgch[i] = (cid & 7) ^ (srow[i] & 7);
  }

  const int nkv = qt + 1;
  for (int t = 0; t < nkv; ++t) {
    const int kv0 = t * 64;
#pragma unroll
    for (int i = 0; i < 2; ++i) {
      char* lk = (char*)Kls + (w * 64 + i * 256) * 16;
      async16(Kh + (size_t)(kv0 + srow[i]) * 64 + sgch[i] * 8, lk);
      char* lv = (char*)Vls + (w * 64 + i * 256) * 16;
      async16(Vh + (size_t)srow[i] * 2048 + kv0 + sgch[i] * 8, lv);
    }
    __syncthreads();

    // QK^T: 16 q-rows x 64 kv-cols per wave
    f32x4 sc[4];
#pragma unroll
    for (int ct = 0; ct < 4; ++ct) {
      int row = ct * 16 + lr;
      int rs = row & 7;
      bf16x8 b0 = *(const bf16x8*)(Kls + row * 64 + (lkb ^ rs) * 8);
      bf16x8 b1 = *(const bf16x8*)(Kls + row * 64 + ((lkb + 4) ^ rs) * 8);
      f32x4 z = {};
      z = __builtin_amdgcn_mfma_f32_16x16x32_bf16(aQ[0], b0, z, 0, 0, 0);
      z = __builtin_amdgcn_mfma_f32_16x16x32_bf16(aQ[1], b1, z, 0, 0, 0);
      sc[ct] = z;
    }

    if (t == qt) {  // diagonal tile: mask col > row
#pragma unroll
      for (int ct = 0; ct < 4; ++ct) {
        int col = kv0 + ct * 16 + lr;
#pragma unroll
        for (int r = 0; r < 4; ++r) {
          int qr = q0 + w * 16 + lkb * 4 + r;
          if (col > qr) sc[ct][r] = -1e30f;
        }
      }
    }

    // online softmax; row stats live in the 16-lane col group
#pragma unroll
    for (int r = 0; r < 4; ++r) {
      float mt = fmaxf(fmaxf(sc[0][r], sc[1][r]), fmaxf(sc[2][r], sc[3][r]));
      mt = fmaxf(mt, __shfl_xor(mt, 1));
      mt = fmaxf(mt, __shfl_xor(mt, 2));
      mt = fmaxf(mt, __shfl_xor(mt, 4));
      mt = fmaxf(mt, __shfl_xor(mt, 8));
      float mnew = fmaxf(mrow[r], mt);
      float a = exp2f((mrow[r] - mnew) * LOG2E);
      mrow[r] = mnew;
      float rsum = 0.f;
#pragma unroll
      for (int ct = 0; ct < 4; ++ct) {
        float p = exp2f((sc[ct][r] - mnew) * LOG2E);
        sc[ct][r] = p;
        rsum += p;
      }
      rsum += __shfl_xor(rsum, 1);
      rsum += __shfl_xor(rsum, 2);
      rsum += __shfl_xor(rsum, 4);
      rsum += __shfl_xor(rsum, 8);
      lrow[r] = lrow[r] * a + rsum;
#pragma unroll
      for (int dt = 0; dt < 4; ++dt) acc[dt][r] *= a;
    }

    // P (C-layout) -> LDS -> A-fragment layout (wave-private, stride 72 kills conflicts)
    u16* pw = &Pls[w][0];
#pragma unroll
    for (int ct = 0; ct < 4; ++ct)
#pragma unroll
      for (int r = 0; r < 4; ++r)
        pw[(lkb * 4 + r) * 72 + ct * 16 + lr] = f2bf(sc[ct][r]);

    bf16x8 aP0 = *(const bf16x8*)(pw + lr * 72 + lkb * 8);
    bf16x8 aP1 = *(const bf16x8*)(pw + lr * 72 + lkb * 8 + 32);

    // PV: O += P[16x64] * V[64x64]
#pragma unroll
    for (int dt = 0; dt < 4; ++dt) {
      int row = dt * 16 + lr;
      int rs = row & 7;
      bf16x8 v0 = *(const bf16x8*)(Vls + row * 64 + (lkb ^ rs) * 8);
      bf16x8 v1 = *(const bf16x8*)(Vls + row * 64 + ((lkb + 4) ^ rs) * 8);
      acc[dt] = __builtin_amdgcn_mfma_f32_16x16x32_bf16(aP0, v0, acc[dt], 0, 0, 0);
      acc[dt] = __builtin_amdgcn_mfma_f32_16x16x32_bf16(aP1, v1, acc[dt], 0, 0, 0);
    }
    __syncthreads();
  }

  const int b = bh >> 4, h = bh & 15;
#pragma unroll
  for (int r = 0; r < 4; ++r) {
    float rl = 1.0f / lrow[r];
    int qr = q0 + w * 16 + lkb * 4 + r;
    size_t base = ((size_t)(b * 2048 + qr)) * 1024 + h * 64;
#pragma unroll
    for (int dt = 0; dt < 4; ++dt)
      ctx[base + dt * 16 + lr] = f2bf(acc[dt][r] * rl);
  }
}

extern "C" void kernel_launch(void* const* d_in, const int* in_sizes, int n_in,
                              void* d_out, int out_size, void* d_ws, size_t ws_size,
                              hipStream_t stream) {
  (void)in_sizes; (void)n_in; (void)out_size; (void)ws_size;
  const float* x = (const float*)d_in[0];
  const float* qkv_w = (const float*)d_in[1];
  const float* qkv_b = (const float*)d_in[2];
  const float* out_w = (const float*)d_in[3];
  const float* out_b = (const float*)d_in[4];
  float* out = (float*)d_out;

  char* ws = (char*)d_ws;
  u16* xb   = (u16*)(ws);                 // 4096*1024*2 = 8 MiB
  u16* wqkv = (u16*)(ws + 8388608);       // 3072*1024*2 = 6 MiB
  u16* wout = (u16*)(ws + 14680064);      // 1024*1024*2 = 2 MiB
  u16* Qb   = (u16*)(ws + 16777216);      // 8 MiB  [BH][S][64]
  u16* Kb   = (u16*)(ws + 25165824);      // 8 MiB  [BH][S][64]
  u16* Vtb  = (u16*)(ws + 33554432);      // 8 MiB  [BH][64][S]
  u16* ctx  = (u16*)(ws + 41943040);      // 8 MiB  [B,S,1024]

  cast_f32_bf16<<<4096, 256, 0, stream>>>(x, xb, 1048576);
  cast_f32_bf16<<<3072, 256, 0, stream>>>(qkv_w, wqkv, 786432);
  cast_f32_bf16<<<1024, 256, 0, stream>>>(out_w, wout, 262144);

  gemm_nt<0><<<768, 256, 0, stream>>>(xb, wqkv, 4096, 3072, 1024, qkv_b,
                                      Qb, Kb, Vtb, nullptr, 24);
  flash_attn<<<1024, 256, 0, stream>>>(Qb, Kb, Vtb, ctx);
  gemm_nt<1><<<256, 256, 0, stream>>>(ctx, wout, 4096, 1024, 1024, out_b,
                                      nullptr, nullptr, nullptr, out, 8);
}

// Round 4
// 200.665 us; speedup vs baseline: 1.1433x; 1.1433x over previous
//
#include <hip/hip_runtime.h>

typedef unsigned short u16;
typedef __bf16 bf16x8 __attribute__((ext_vector_type(8)));
typedef float f32x4 __attribute__((ext_vector_type(4)));

#define LOG2E 1.44269504088896340736f

__device__ __forceinline__ u16 f2bf(float f) {
  unsigned int u = __builtin_bit_cast(unsigned int, f);
  u += 0x7FFFu + ((u >> 16) & 1u);
  return (u16)(u >> 16);
}

__device__ __forceinline__ unsigned int cvtpk_bf16(float lo, float hi) {
  unsigned int r;
  asm("v_cvt_pk_bf16_f32 %0, %1, %2" : "=v"(r) : "v"(lo), "v"(hi));
  return r;
}

__device__ __forceinline__ void async16(const void* g, void* l) {
  __builtin_amdgcn_global_load_lds((void*)g, (void*)l, 16, 0, 0);
}

// ---------------- fused cast fp32 -> bf16 for x, qkv_w, out_w ----------------
__global__ void cast_all(const float* __restrict__ x, const float* __restrict__ w1,
                         const float* __restrict__ w2, u16* __restrict__ xb,
                         u16* __restrict__ w1b, u16* __restrict__ w2b) {
  int i = blockIdx.x * blockDim.x + threadIdx.x;
  const float* s; u16* d; int j;
  if (i < 1048576)      { s = x;  d = xb;  j = i; }
  else if (i < 1835008) { s = w1; d = w1b; j = i - 1048576; }
  else                  { s = w2; d = w2b; j = i - 1835008; }
  float4 v = ((const float4*)s)[j];
  union { u16 s4[4]; uint2 u; } o;
  o.s4[0] = f2bf(v.x); o.s4[1] = f2bf(v.y); o.s4[2] = f2bf(v.z); o.s4[3] = f2bf(v.w);
  ((uint2*)d)[j] = o.u;
}

// ---------------- bf16 NT GEMM: C[m][n] = sum_k A[m][k] * Bw[n][k] ----------------
// 128xBN tile, BK=32, 4 waves each 64x(BN/2). EPI 0: QKV scatter. EPI 1: fp32 out + bias.
template <int EPI, int BN>
__global__ __launch_bounds__(256)
void gemm_nt(const u16* __restrict__ A, const u16* __restrict__ Bw,
             int M, int N, int K, const float* __restrict__ bias,
             u16* __restrict__ qo, u16* __restrict__ ko, u16* __restrict__ vto,
             float* __restrict__ out, int ntn) {
  __shared__ __align__(16) u16 As[128 * 32];
  __shared__ __align__(16) u16 Bs[BN * 32];
  constexpr int JN = BN / 32;       // wave n-subtiles
  constexpr int NB = (BN * 4) / 256;  // B staging issues per thread
  const int tid = threadIdx.x;
  const int w = tid >> 6, lane = tid & 63;
  const int lr = lane & 15, lkb = lane >> 4;
  const int bx = blockIdx.x;
  const int mt = bx / ntn, nt = bx % ntn;
  const int m0 = mt * 128, n0 = nt * BN;
  const int wm = (w >> 1) * 64, wn = (w & 1) * (BN / 2);

  f32x4 acc[4][JN] = {};

  int srow[2], sgch[2];
#pragma unroll
  for (int i = 0; i < 2; ++i) {
    int cid = tid + i * 256;          // 16B chunks, 4 chunks per 64B row
    srow[i] = cid >> 2;
    sgch[i] = (cid & 3) ^ (srow[i] & 3);
  }

  for (int k0 = 0; k0 < K; k0 += 32) {
#pragma unroll
    for (int i = 0; i < 2; ++i) {
      char* la = (char*)As + (w * 64 + i * 256) * 16;
      async16(A + (size_t)(m0 + srow[i]) * K + k0 + sgch[i] * 8, la);
    }
#pragma unroll
    for (int i = 0; i < NB; ++i) {
      char* lb = (char*)Bs + (w * 64 + i * 256) * 16;
      async16(Bw + (size_t)(n0 + srow[i]) * K + k0 + sgch[i] * 8, lb);
    }
    __syncthreads();

    bf16x8 af[4], bfr[JN];
#pragma unroll
    for (int i = 0; i < 4; ++i) {
      int ra = wm + i * 16 + lr;
      af[i] = *(const bf16x8*)(As + ra * 32 + (lkb ^ (ra & 3)) * 8);
    }
#pragma unroll
    for (int j = 0; j < JN; ++j) {
      int rb = wn + j * 16 + lr;
      bfr[j] = *(const bf16x8*)(Bs + rb * 32 + (lkb ^ (rb & 3)) * 8);
    }
#pragma unroll
    for (int i = 0; i < 4; ++i)
#pragma unroll
      for (int j = 0; j < JN; ++j)
        acc[i][j] = __builtin_amdgcn_mfma_f32_16x16x32_bf16(af[i], bfr[j], acc[i][j], 0, 0, 0);
    __syncthreads();
  }

  if constexpr (EPI == 0) {
    const int which = n0 >> 10;  // uniform per block
    const float qscale = (which == 0) ? 0.125f : 1.0f;
#pragma unroll
    for (int i = 0; i < 4; ++i) {
#pragma unroll
      for (int j = 0; j < JN; ++j) {
        int n = n0 + wn + j * 16 + lr;
        float bv = bias[n];
        int d = n & 1023, h = d >> 6, dd = d & 63;
#pragma unroll
        for (int r = 0; r < 4; ++r) {
          int m = m0 + wm + i * 16 + lkb * 4 + r;
          int b = m >> 11, s = m & 2047;
          int bh = b * 16 + h;
          u16 val = f2bf((acc[i][j][r] + bv) * qscale);
          if (which == 0)      qo[(bh * 2048 + s) * 64 + dd] = val;
          else if (which == 1) ko[(bh * 2048 + s) * 64 + dd] = val;
          else                 vto[(bh * 64 + dd) * 2048 + s] = val;
        }
      }
    }
  } else {
#pragma unroll
    for (int i = 0; i < 4; ++i)
#pragma unroll
      for (int j = 0; j < JN; ++j) {
        int n = n0 + wn + j * 16 + lr;
        float bv = bias[n];
#pragma unroll
        for (int r = 0; r < 4; ++r) {
          int m = m0 + wm + i * 16 + lkb * 4 + r;
          out[(size_t)m * N + n] = acc[i][j][r] + bv;
        }
      }
  }
}

// ---------------- causal flash attention, swapped-QK^T (lane-local softmax) --------
// Q,K: [BH=32][S=2048][64] bf16 (Q pre-scaled). Vt: [BH][64][S]. ctx: [B,S,1024] bf16.
// Block: 64 q-rows (4 waves x 16 q). KV tile 64, double-buffered, 1 barrier/tile.
__global__ __launch_bounds__(256)
void flash_attn(const u16* __restrict__ Q, const u16* __restrict__ Kg,
                const u16* __restrict__ Vt, u16* __restrict__ ctx) {
  __shared__ __align__(16) u16 Kls[2][64 * 64];
  __shared__ __align__(16) u16 Vls[2][64 * 64];
  const int tid = threadIdx.x;
  const int w = tid >> 6, lane = tid & 63;
  const int lr = lane & 15, lkb = lane >> 4;
  const int bid = blockIdx.x;
  const int qt = 31 - (bid >> 5);  // heavy q-tiles first
  const int bh = bid & 31;
  const int q0 = qt * 64;
  const u16* Qh = Q + (size_t)bh * 2048 * 64;
  const u16* Kh = Kg + (size_t)bh * 2048 * 64;
  const u16* Vh = Vt + (size_t)bh * 2048 * 64;  // [64][2048]

  // Q as B-fragment: lane holds Q[q0+w*16+lr][kk*32 + lkb*8 + j]
  bf16x8 aQ[2];
#pragma unroll
  for (int kk = 0; kk < 2; ++kk)
    aQ[kk] = *(const bf16x8*)(Qh + (q0 + w * 16 + lr) * 64 + kk * 32 + lkb * 8);

  f32x4 acc[4] = {};          // O^T tiles: lane holds O[q=lr][d = dt*16+lkb*4+r]
  float m_r = -1e30f, l_r = 0.f;  // per-lane (per-q) softmax state

  int srow[2], sgch[2];
#pragma unroll
  for (int i = 0; i < 2; ++i) {
    int cid = tid + i * 256;   // 8 chunks per 128B row
    srow[i] = cid >> 3;
    sgch[i] = (cid & 7) ^ (srow[i] & 7);
  }

  const int nkv = qt + 1;

  // prologue stage tile 0 into buf 0
  {
#pragma unroll
    for (int i = 0; i < 2; ++i) {
      char* lk = (char*)&Kls[0][0] + (w * 64 + i * 256) * 16;
      async16(Kh + (size_t)srow[i] * 64 + sgch[i] * 8, lk);
      char* lv = (char*)&Vls[0][0] + (w * 64 + i * 256) * 16;
      async16(Vh + (size_t)srow[i] * 2048 + sgch[i] * 8, lv);
    }
  }
  __syncthreads();

  for (int t = 0; t < nkv; ++t) {
    const int cur = t & 1;
    if (t + 1 < nkv) {
      const int kv1 = (t + 1) * 64;
#pragma unroll
      for (int i = 0; i < 2; ++i) {
        char* lk = (char*)&Kls[cur ^ 1][0] + (w * 64 + i * 256) * 16;
        async16(Kh + (size_t)(kv1 + srow[i]) * 64 + sgch[i] * 8, lk);
        char* lv = (char*)&Vls[cur ^ 1][0] + (w * 64 + i * 256) * 16;
        async16(Vh + (size_t)srow[i] * 2048 + kv1 + sgch[i] * 8, lv);
      }
    }
    const u16* Kb = &Kls[cur][0];
    const u16* Vb = &Vls[cur][0];

    // S^T = K * Q^T : lane holds S[kv = ct*16+lkb*4+r][q = lr]
    f32x4 sc[4];
#pragma unroll
    for (int ct = 0; ct < 4; ++ct) {
      int row = ct * 16 + lr;
      int rs = row & 7;
      bf16x8 k0 = *(const bf16x8*)(Kb + row * 64 + (lkb ^ rs) * 8);
      bf16x8 k1 = *(const bf16x8*)(Kb + row * 64 + ((lkb + 4) ^ rs) * 8);
      f32x4 z = {};
      z = __builtin_amdgcn_mfma_f32_16x16x32_bf16(k0, aQ[0], z, 0, 0, 0);
      z = __builtin_amdgcn_mfma_f32_16x16x32_bf16(k1, aQ[1], z, 0, 0, 0);
      sc[ct] = z;
    }

    if (t == qt) {  // diagonal: mask kv_local > q_local
#pragma unroll
      for (int ct = 0; ct < 4; ++ct)
#pragma unroll
        for (int r = 0; r < 4; ++r)
          if (ct * 16 + lkb * 4 + r > w * 16 + lr) sc[ct][r] = -1e30f;
    }

    // lane-local row max (16 values) + 2 cross-lane combines
    float g0 = fmaxf(fmaxf(sc[0][0], sc[0][1]), fmaxf(sc[0][2], sc[0][3]));
    float g1 = fmaxf(fmaxf(sc[1][0], sc[1][1]), fmaxf(sc[1][2], sc[1][3]));
    float g2 = fmaxf(fmaxf(sc[2][0], sc[2][1]), fmaxf(sc[2][2], sc[2][3]));
    float g3 = fmaxf(fmaxf(sc[3][0], sc[3][1]), fmaxf(sc[3][2], sc[3][3]));
    float mt = fmaxf(fmaxf(g0, g1), fmaxf(g2, g3));
    mt = fmaxf(mt, __shfl_xor(mt, 16));
    mt = fmaxf(mt, __shfl_xor(mt, 32));

    // defer-max: only rescale when some row grew past threshold
    if (!__all(mt <= m_r + 8.0f)) {
      float mnew = fmaxf(m_r, mt);
      float a = exp2f((m_r - mnew) * LOG2E);
      l_r *= a;
#pragma unroll
      for (int dt = 0; dt < 4; ++dt) acc[dt] *= a;
      m_r = mnew;
    }
    const float mls = m_r * LOG2E;
    float rsum = 0.f;
#pragma unroll
    for (int ct = 0; ct < 4; ++ct)
#pragma unroll
      for (int r = 0; r < 4; ++r) {
        float p = exp2f(__builtin_fmaf(sc[ct][r], LOG2E, -mls));
        sc[ct][r] = p;
        rsum += p;
      }
    rsum += __shfl_xor(rsum, 16);
    rsum += __shfl_xor(rsum, 32);
    l_r += rsum;

    // pack P to bf16 pairs: u[ct][0] = kv {ct*16+lkb*4+0,1}, u[ct][1] = {+2,+3}
    unsigned int u[4][2];
#pragma unroll
    for (int ct = 0; ct < 4; ++ct) {
      u[ct][0] = cvtpk_bf16(sc[ct][0], sc[ct][1]);
      u[ct][1] = cvtpk_bf16(sc[ct][2], sc[ct][3]);
    }

    // redistribute to B-frag layout: lane needs P[q=lr][kv = c*32 + lkb*8 + j]
    const int s0 = ((lkb & 1) << 5) + lr;
    const int s1 = s0 + 16;
    const int hi = lkb >> 1;
    bf16x8 Pf[2];
#pragma unroll
    for (int c = 0; c < 2; ++c) {
      const int c2 = c * 2;
      unsigned x0 = (unsigned)__shfl((int)u[c2][0], s0, 64);
      unsigned x1 = (unsigned)__shfl((int)u[c2][1], s0, 64);
      unsigned x2 = (unsigned)__shfl((int)u[c2][0], s1, 64);
      unsigned x3 = (unsigned)__shfl((int)u[c2][1], s1, 64);
      unsigned y0 = (unsigned)__shfl((int)u[c2 + 1][0], s0, 64);
      unsigned y1 = (unsigned)__shfl((int)u[c2 + 1][1], s0, 64);
      unsigned y2 = (unsigned)__shfl((int)u[c2 + 1][0], s1, 64);
      unsigned y3 = (unsigned)__shfl((int)u[c2 + 1][1], s1, 64);
      uint4 bb;
      bb.x = hi ? y0 : x0;
      bb.y = hi ? y1 : x1;
      bb.z = hi ? y2 : x2;
      bb.w = hi ? y3 : x3;
      Pf[c] = __builtin_bit_cast(bf16x8, bb);
    }

    // O^T += V^T * P : A-frag = V^T[d][kv chunk], B-frag = Pf
#pragma unroll
    for (int dt = 0; dt < 4; ++dt) {
      int row = dt * 16 + lr;
      int rs = row & 7;
      bf16x8 v0 = *(const bf16x8*)(Vb + row * 64 + (lkb ^ rs) * 8);
      bf16x8 v1 = *(const bf16x8*)(Vb + row * 64 + ((lkb + 4) ^ rs) * 8);
      acc[dt] = __builtin_amdgcn_mfma_f32_16x16x32_bf16(v0, Pf[0], acc[dt], 0, 0, 0);
      acc[dt] = __builtin_amdgcn_mfma_f32_16x16x32_bf16(v1, Pf[1], acc[dt], 0, 0, 0);
    }
    __syncthreads();  // drains vmcnt(0): next tile's staged data ready
  }

  const float rl = 1.0f / l_r;
  const int b = bh >> 4, h = bh & 15;
  const int q = q0 + w * 16 + lr;
  const size_t base = ((size_t)(b * 2048 + q)) * 1024 + h * 64;
#pragma unroll
  for (int dt = 0; dt < 4; ++dt) {
    uint2 o;
    o.x = cvtpk_bf16(acc[dt][0] * rl, acc[dt][1] * rl);
    o.y = cvtpk_bf16(acc[dt][2] * rl, acc[dt][3] * rl);
    *(uint2*)(ctx + base + dt * 16 + lkb * 4) = o;
  }
}

extern "C" void kernel_launch(void* const* d_in, const int* in_sizes, int n_in,
                              void* d_out, int out_size, void* d_ws, size_t ws_size,
                              hipStream_t stream) {
  (void)in_sizes; (void)n_in; (void)out_size; (void)ws_size;
  const float* x = (const float*)d_in[0];
  const float* qkv_w = (const float*)d_in[1];
  const float* qkv_b = (const float*)d_in[2];
  const float* out_w = (const float*)d_in[3];
  const float* out_b = (const float*)d_in[4];
  float* out = (float*)d_out;

  char* ws = (char*)d_ws;
  u16* xb   = (u16*)(ws);                 // 8 MiB
  u16* wqkv = (u16*)(ws + 8388608);       // 6 MiB
  u16* wout = (u16*)(ws + 14680064);      // 2 MiB
  u16* Qb   = (u16*)(ws + 16777216);      // 8 MiB  [BH][S][64]
  u16* Kb   = (u16*)(ws + 25165824);      // 8 MiB  [BH][S][64]
  u16* Vtb  = (u16*)(ws + 33554432);      // 8 MiB  [BH][64][S]
  u16* ctx  = (u16*)(ws + 41943040);      // 8 MiB  [B,S,1024]

  cast_all<<<8192, 256, 0, stream>>>(x, qkv_w, out_w, xb, wqkv, wout);

  gemm_nt<0, 128><<<768, 256, 0, stream>>>(xb, wqkv, 4096, 3072, 1024, qkv_b,
                                           Qb, Kb, Vtb, nullptr, 24);
  flash_attn<<<1024, 256, 0, stream>>>(Qb, Kb, Vtb, ctx);
  gemm_nt<1, 64><<<512, 256, 0, stream>>>(ctx, wout, 4096, 1024, 1024, out_b,
                                          nullptr, nullptr, nullptr, out, 16);
}